// Round 2
// baseline (718.401 us; speedup 1.0000x reference)
//
#include <hip/hip_runtime.h>
#include <stdint.h>

#define B_   16
#define MC   2048
#define MT   4096
#define E_   512
#define NRELS 69

typedef __attribute__((ext_vector_type(8))) short bf16x8;
typedef __attribute__((ext_vector_type(4))) float floatx4;

typedef __attribute__((address_space(1))) const void gvoid_t;
typedef __attribute__((address_space(3))) void lvoid_t;

__device__ inline float b2f(ushort u) {
  union { uint32_t i; float f; } x; x.i = ((uint32_t)u) << 16; return x.f;
}
__device__ inline ushort f2b(float f) {
  union { float f; uint32_t u; } v; v.f = f;
  uint32_t r = (v.u + 0x7fffu + ((v.u >> 16) & 1u)) >> 16;
  return (ushort)r;
}

// async global->LDS, 16B per lane (m97 pattern: linear LDS dest = wavebase + lane*16)
__device__ inline void gl2lds(const ushort* g, ushort* l) {
  __builtin_amdgcn_global_load_lds((gvoid_t*)g, (lvoid_t*)l, 16, 0, 0);
}

// block-local dtype probe: fp32 data read as ushorts has random exponent bytes in
// the low halves; bf16 0.02-scale data never has exp >= 0xC0 (2^65).
__device__ inline int block_detect(const ushort* ct) {
  __shared__ int sflag;
  if (threadIdx.x == 0) sflag = 0;
  __syncthreads();
  int bad = 0;
  for (int j = threadIdx.x; j < 1024; j += 256) {
    int e = (ct[j] >> 7) & 0xFF;
    if (e >= 0xC0) bad = 1;
  }
  if (bad) sflag = 1;
  __syncthreads();
  return sflag;
}

__device__ inline void cvt8(const void* src, ushort* dst, int c, int flag) {
  if (flag) {
    const float* s = (const float*)src + (size_t)c * 8;
    float4 a = *(const float4*)s, b = *(const float4*)(s + 4);
    uint32_t p0 = (uint32_t)f2b(a.x) | ((uint32_t)f2b(a.y) << 16);
    uint32_t p1 = (uint32_t)f2b(a.z) | ((uint32_t)f2b(a.w) << 16);
    uint32_t p2 = (uint32_t)f2b(b.x) | ((uint32_t)f2b(b.y) << 16);
    uint32_t p3 = (uint32_t)f2b(b.z) | ((uint32_t)f2b(b.w) << 16);
    *(uint4*)(dst + (size_t)c * 8) = make_uint4(p0, p1, p2, p3);
  } else {
    *(uint4*)(dst + (size_t)c * 8) = *(const uint4*)((const ushort*)src + (size_t)c * 8);
  }
}

// ---------- fused preprocessing: weight/rtab cvt + h gather + degree count ----------
#define NW8 (2 * E_ * E_ / 8)   // 65536 chunks per weight pair
#define NR8 (NRELS * E_ / 8)    // 4416
#define NGH (B_ * MC * 64)      // 2097152
#define NCT (B_ * MT)           // 65536
#define SEC1 (NW8)
#define SEC2 (2 * NW8)
#define SEC3 (3 * NW8)
#define SEC4 (SEC3 + NR8)
#define SEC5 (SEC4 + NGH)
#define STOT (SEC5 + NCT)

__global__ void preproc_k(const void* __restrict__ ct, const void* __restrict__ rt,
                          const void* __restrict__ Ws, const void* __restrict__ Wn,
                          const void* __restrict__ Wr,
                          const int* __restrict__ cids, const int* __restrict__ heads,
                          const int* __restrict__ tails, const int* __restrict__ labels,
                          ushort* __restrict__ Wsb, ushort* __restrict__ Wnb,
                          ushort* __restrict__ Wrb, ushort* __restrict__ rtab0,
                          ushort* __restrict__ h0, int* __restrict__ cnt) {
  int flag = block_detect((const ushort*)ct);
  int c = blockIdx.x * 256 + threadIdx.x;
  if (c >= STOT) return;
  if (c < SEC3) {                       // weight conversion
    if (c < SEC1)       cvt8(Ws, Wsb, c, flag);
    else if (c < SEC2)  cvt8(Wn, Wnb, c - SEC1, flag);
    else                cvt8(Wr, Wrb, c - SEC2, flag);
  } else if (c < SEC4) {                // relation table conversion
    cvt8(rt, rtab0, c - SEC3, flag);
  } else if (c < SEC5) {                // gather h0 rows
    int g = c - SEC4;
    int row = g >> 6, col = (g & 63) << 3;
    int src = cids[row];
    if (flag) {
      const float* s = (const float*)ct + (size_t)src * E_ + col;
      float4 a = *(const float4*)s, b = *(const float4*)(s + 4);
      uint32_t p0 = (uint32_t)f2b(a.x) | ((uint32_t)f2b(a.y) << 16);
      uint32_t p1 = (uint32_t)f2b(a.z) | ((uint32_t)f2b(a.w) << 16);
      uint32_t p2 = (uint32_t)f2b(b.x) | ((uint32_t)f2b(b.y) << 16);
      uint32_t p3 = (uint32_t)f2b(b.z) | ((uint32_t)f2b(b.w) << 16);
      *(uint4*)(h0 + (size_t)row * E_ + col) = make_uint4(p0, p1, p2, p3);
    } else {
      *(uint4*)(h0 + (size_t)row * E_ + col) =
          *(const uint4*)((const ushort*)ct + (size_t)src * E_ + col);
    }
  } else {                              // degree count (hop-invariant)
    int t = c - SEC5;
    if (labels[t] != -1) {
      int b = t >> 12;
      atomicAdd(&cnt[b * MC + heads[t]], 1);
      atomicAdd(&cnt[b * MC + tails[t]], 1);
    }
  }
}

// ---------- exclusive scan of 32768 counts -> offs[0..n]; also inv = 1/max(cnt,1) ----------
__global__ void scan_inv_k(const int* __restrict__ cnt, int* __restrict__ offs,
                           float* __restrict__ inv) {
  __shared__ int part[1024];
  int tid = threadIdx.x;
  const int CH = (B_ * MC) / 1024;   // 32
  int base = tid * CH, s = 0;
  for (int i = 0; i < CH; ++i) s += cnt[base + i];
  part[tid] = s;
  __syncthreads();
  for (int off = 1; off < 1024; off <<= 1) {
    int v = (tid >= off) ? part[tid - off] : 0;
    __syncthreads();
    part[tid] += v;
    __syncthreads();
  }
  int run = (tid == 0) ? 0 : part[tid - 1];
  for (int i = 0; i < CH; ++i) {
    int cc = cnt[base + i];
    offs[base + i] = run;
    inv[base + i] = 1.0f / (float)(cc > 1 ? cc : 1);
    run += cc;
  }
  if (tid == 1023) offs[B_ * MC] = run;
}

// ---------- CSR fill: one atomic per endpoint ----------
__global__ void fill_k(const int* __restrict__ head, const int* __restrict__ tail,
                       const int* __restrict__ rid, const int* __restrict__ labels,
                       const int* __restrict__ offs, int* __restrict__ cursor,
                       int* __restrict__ edges) {
  int t = blockIdx.x * blockDim.x + threadIdx.x;
  if (t >= B_ * MT) return;
  if (labels[t] == -1) return;
  int b = t >> 12;
  int hb = b * MC + head[t], tb = b * MC + tail[t];
  int r = rid[t];
  int p = atomicAdd(&cursor[tb], 1);
  edges[offs[tb] + p] = head[t] | (r << 16);    // message head->tail
  p = atomicAdd(&cursor[hb], 1);
  edges[offs[hb] + p] = tail[t] | (r << 16);    // message tail->head
}

// ---------- gather messages: one wave per concept row; zero atomics ----------
__global__ void gather_msg_k(const ushort* __restrict__ h, const ushort* __restrict__ rtab,
                             const int* __restrict__ edges, const int* __restrict__ offs,
                             const float* __restrict__ inv, ushort* __restrict__ updb) {
  int row = blockIdx.x * 4 + (threadIdx.x >> 6);   // b*MC + c
  int lane = threadIdx.x & 63;
  int col = lane << 3;                             // 64 lanes x 8 cols = 512
  int beg = offs[row], end = offs[row + 1];
  int b = row >> 11;                               // MC = 2048
  float acc[8];
#pragma unroll
  for (int i = 0; i < 8; ++i) acc[i] = 0.f;
  const ushort* hbase = h + (size_t)b * MC * E_ + col;
  for (int e = beg; e < end; ++e) {
    int ent = edges[e];                            // uniform across wave -> broadcast
    int other = ent & 0xffff, rid = ent >> 16;
    uint4 vh = *(const uint4*)(hbase + (size_t)other * E_);    // coalesced 1KB row read
    uint4 vr = *(const uint4*)(rtab + (size_t)rid * E_ + col); // 69KB table: cache-hot
    uint32_t wh[4] = {vh.x, vh.y, vh.z, vh.w};
    uint32_t wr[4] = {vr.x, vr.y, vr.z, vr.w};
#pragma unroll
    for (int i = 0; i < 4; ++i) {
      acc[2 * i]     += b2f((ushort)(wh[i] & 0xffff)) - b2f((ushort)(wr[i] & 0xffff));
      acc[2 * i + 1] += b2f((ushort)(wh[i] >> 16))    - b2f((ushort)(wr[i] >> 16));
    }
  }
  float s = inv[row];
  uint32_t p[4];
#pragma unroll
  for (int i = 0; i < 4; ++i)
    p[i] = (uint32_t)f2b(acc[2 * i] * s) | ((uint32_t)f2b(acc[2 * i + 1] * s) << 16);
  *(uint4*)(updb + (size_t)row * E_ + col) = make_uint4(p[0], p[1], p[2], p[3]);
}

// ---------- fused 2-hop relation GEMM: rtab1 = rtab0@Wr0^T; rtab2 = rtab1@Wr1^T ----------
// Row-wise independent chain: block n carries its row through both hops in LDS.
__global__ void rel2_gemm_k(const ushort* __restrict__ rtab0, const ushort* __restrict__ Wr,
                            ushort* __restrict__ rtab1, ushort* __restrict__ rtab2) {
  __shared__ float arow[E_];
  int n = blockIdx.x;
  int tid = threadIdx.x;
  for (int k = tid; k < E_; k += 256) arow[k] = b2f(rtab0[n * E_ + k]);
  __syncthreads();
  for (int hp = 0; hp < 2; ++hp) {
    const ushort* W = Wr + (size_t)hp * E_ * E_;
    int ca = tid, cb = tid + 256;
    float acc0 = 0.f, acc1 = 0.f;
    const ushort* wa = W + (size_t)ca * E_;
    const ushort* wb = W + (size_t)cb * E_;
    for (int k = 0; k < E_; k += 8) {
      uint4 w8a = *(const uint4*)(wa + k);
      uint4 w8b = *(const uint4*)(wb + k);
      uint32_t va[4] = {w8a.x, w8a.y, w8a.z, w8a.w};
      uint32_t vb[4] = {w8b.x, w8b.y, w8b.z, w8b.w};
#pragma unroll
      for (int i = 0; i < 4; ++i) {
        float a0 = arow[k + 2 * i], a1 = arow[k + 2 * i + 1];
        acc0 += a0 * b2f((ushort)(va[i] & 0xffff)) + a1 * b2f((ushort)(va[i] >> 16));
        acc1 += a0 * b2f((ushort)(vb[i] & 0xffff)) + a1 * b2f((ushort)(vb[i] >> 16));
      }
    }
    __syncthreads();                    // all reads of arow complete before overwrite
    ushort ra = f2b(acc0), rb = f2b(acc1);
    ushort* o = hp ? rtab2 : rtab1;
    o[n * E_ + ca] = ra;
    o[n * E_ + cb] = rb;
    arow[ca] = b2f(ra);                 // bf16 round-trip matches prior numerics
    arow[cb] = b2f(rb);
    __syncthreads();
  }
}

// ---------- fused h-GEMM: C = relu( A0@W0^T + A1@W1^T ), all-bf16 inputs ----------
// Staging via global_load_lds width-16 into LINEAR LDS (m97 ladder step: 517->874 TF).
#define BM 128
#define BN 128
#define BK 64

__global__ __launch_bounds__(256) void gemm_h_k(
    const ushort* __restrict__ A0, const ushort* __restrict__ W0,
    const ushort* __restrict__ A1, const ushort* __restrict__ W1,
    ushort* __restrict__ C) {
  const int N = E_, K = E_;
  __shared__ __align__(16) ushort As[BM * BK];
  __shared__ __align__(16) ushort Bs[BN * BK];
  int nbn = N / BN;
  int bm = blockIdx.x / nbn, bn = blockIdx.x % nbn;
  int tid = threadIdx.x;
  int lane = tid & 63, wid = tid >> 6;
  int wm = (wid >> 1) * 64, wn = (wid & 1) * 64;
  int lrow = lane & 15, lq = lane >> 4;

  floatx4 acc[4][4];
#pragma unroll
  for (int i = 0; i < 4; ++i)
#pragma unroll
    for (int j = 0; j < 4; ++j) acc[i][j] = (floatx4)(0.0f);

  for (int pass = 0; pass < 2; ++pass) {
    const ushort* Am = pass ? A1 : A0;
    const ushort* Wm = pass ? W1 : W0;
    for (int k0 = 0; k0 < K; k0 += BK) {
#pragma unroll
      for (int i = 0; i < 4; ++i) {
        int c = tid + i * 256;                    // chunk of 8 shorts; lane-contiguous
        int row = c >> 3, col = (c & 7) << 3;
        gl2lds(Am + (size_t)(bm * BM + row) * K + k0 + col, As + row * BK + col);
      }
#pragma unroll
      for (int i = 0; i < 4; ++i) {
        int c = tid + i * 256;
        int row = c >> 3, col = (c & 7) << 3;
        gl2lds(Wm + (size_t)(bn * BN + row) * K + k0 + col, Bs + row * BK + col);
      }
      __syncthreads();                            // compiler drains vmcnt before barrier
#pragma unroll
      for (int kk = 0; kk < BK; kk += 32) {
        bf16x8 af[4], bfr[4];
#pragma unroll
        for (int mi = 0; mi < 4; ++mi)
          af[mi] = *(const bf16x8*)(As + (wm + mi * 16 + lrow) * BK + kk + lq * 8);
#pragma unroll
        for (int ni = 0; ni < 4; ++ni)
          bfr[ni] = *(const bf16x8*)(Bs + (wn + ni * 16 + lrow) * BK + kk + lq * 8);
#pragma unroll
        for (int mi = 0; mi < 4; ++mi)
#pragma unroll
          for (int ni = 0; ni < 4; ++ni)
            acc[mi][ni] = __builtin_amdgcn_mfma_f32_16x16x32_bf16(af[mi], bfr[ni], acc[mi][ni], 0, 0, 0);
      }
      __syncthreads();
    }
  }
  // C/D layout: col=lane&15, row=(lane>>4)*4+reg  [m89/m91 verified]
#pragma unroll
  for (int mi = 0; mi < 4; ++mi)
#pragma unroll
    for (int ni = 0; ni < 4; ++ni)
#pragma unroll
      for (int rg = 0; rg < 4; ++rg) {
        int row = bm * BM + wm + mi * 16 + lq * 4 + rg;
        int col = bn * BN + wn + ni * 16 + lrow;
        C[(size_t)row * N + col] = f2b(fmaxf(acc[mi][ni][rg], 0.0f));
      }
}

// ---------- output assembly: [h[head] | rtab2[rid] | h[tail]], dtype per inline probe ----------
__global__ void out_k(const ushort* __restrict__ h, const ushort* __restrict__ rtab,
                      const int* __restrict__ rid,
                      const int* __restrict__ head, const int* __restrict__ tail,
                      void* __restrict__ out, const ushort* __restrict__ ctab) {
  int flag = block_detect(ctab);
  int gid = blockIdx.x * blockDim.x + threadIdx.x;  // chunks of 8; B*MT*192 total
  int t = gid / 192;
  if (t >= B_ * MT) return;
  int sc = gid - t * 192;
  int sec = sc >> 6;
  int col = (sc & 63) << 3;
  int b = t >> 12;
  const ushort* src;
  if (sec == 0)      src = h + (size_t)(b * MC + head[t]) * E_ + col;
  else if (sec == 1) src = rtab + (size_t)rid[t] * E_ + col;
  else               src = h + (size_t)(b * MC + tail[t]) * E_ + col;
  size_t o = (size_t)t * 1536 + sec * 512 + col;
  if (flag) {
    float* fo = (float*)out + o;
    uint4 v = *(const uint4*)src;
    uint32_t w[4] = {v.x, v.y, v.z, v.w};
    float4 f0, f1;
    f0.x = b2f((ushort)(w[0] & 0xffff)); f0.y = b2f((ushort)(w[0] >> 16));
    f0.z = b2f((ushort)(w[1] & 0xffff)); f0.w = b2f((ushort)(w[1] >> 16));
    f1.x = b2f((ushort)(w[2] & 0xffff)); f1.y = b2f((ushort)(w[2] >> 16));
    f1.z = b2f((ushort)(w[3] & 0xffff)); f1.w = b2f((ushort)(w[3] >> 16));
    *(float4*)fo = f0;
    *(float4*)(fo + 4) = f1;
  } else {
    *(uint4*)((ushort*)out + o) = *(const uint4*)src;
  }
}

extern "C" void kernel_launch(void* const* d_in, const int* in_sizes, int n_in,
                              void* d_out, int out_size, void* d_ws, size_t ws_size,
                              hipStream_t stream) {
  const void* concept_table  = d_in[0];
  const void* relation_table = d_in[1];
  const void* W_s = d_in[2];
  const void* W_n = d_in[3];
  const void* W_r = d_in[4];
  const int* concept_ids  = (const int*)d_in[5];
  const int* relation_ids = (const int*)d_in[6];
  const int* head_idx = (const int*)d_in[7];
  const int* tail_idx = (const int*)d_in[8];
  const int* labels   = (const int*)d_in[9];

  char* ws = (char*)d_ws;
  size_t off = 0;
  auto alloc = [&](size_t bytes) {
    char* p = ws + off;
    off += (bytes + 255) & ~(size_t)255;
    return p;
  };
  // ws total ~68 MB; 32 MB bf16 `upd` scratch lives in d_out (consumed before out_k)
  ushort* h_a    = (ushort*)alloc((size_t)B_ * MC * E_ * 2);   // 32 MB
  ushort* h_b    = (ushort*)alloc((size_t)B_ * MC * E_ * 2);   // 32 MB
  int*    cnt    = (int*)   alloc((size_t)B_ * MC * 4);        // 128 KB
  float*  inv    = (float*) alloc((size_t)B_ * MC * 4);        // 128 KB
  int*    offs   = (int*)   alloc(((size_t)B_ * MC + 1) * 4);  // 128 KB
  int*    cursor = (int*)   alloc((size_t)B_ * MC * 4);        // 128 KB
  int*    edges  = (int*)   alloc((size_t)2 * B_ * MT * 4);    // 512 KB
  ushort* Wsb    = (ushort*)alloc((size_t)2 * E_ * E_ * 2);    // 1 MB
  ushort* Wnb    = (ushort*)alloc((size_t)2 * E_ * E_ * 2);
  ushort* Wrb    = (ushort*)alloc((size_t)2 * E_ * E_ * 2);
  ushort* rtab0  = (ushort*)alloc((size_t)NRELS * E_ * 2);
  ushort* rtab1  = (ushort*)alloc((size_t)NRELS * E_ * 2);
  ushort* rtab2  = (ushort*)alloc((size_t)NRELS * E_ * 2);
  ushort* updb   = (ushort*)d_out;                             // 32 MB scratch in d_out

  hipMemsetAsync(cnt, 0, (size_t)B_ * MC * 4, stream);
  hipMemsetAsync(cursor, 0, (size_t)B_ * MC * 4, stream);

  // fused preprocessing: cvt weights/rtab + gather h0 + degree count
  preproc_k<<<(STOT + 255) / 256, 256, 0, stream>>>(
      concept_table, relation_table, W_s, W_n, W_r,
      concept_ids, head_idx, tail_idx, labels,
      Wsb, Wnb, Wrb, rtab0, h_a, cnt);

  // CSR: scan + inv, then fill
  scan_inv_k<<<1, 1024, 0, stream>>>(cnt, offs, inv);
  fill_k<<<(B_ * MT + 255) / 256, 256, 0, stream>>>(head_idx, tail_idx, relation_ids, labels,
                                                    offs, cursor, edges);

  // relation tables for both hops in one launch
  rel2_gemm_k<<<NRELS, 256, 0, stream>>>(rtab0, Wrb, rtab1, rtab2);

  // hop 0
  gather_msg_k<<<B_ * MC / 4, 256, 0, stream>>>(h_a, rtab0, edges, offs, inv, updb);
  gemm_h_k<<<(B_ * MC / BM) * (E_ / BN), 256, 0, stream>>>(h_a, Wsb, updb, Wnb, h_b);

  // hop 1
  gather_msg_k<<<B_ * MC / 4, 256, 0, stream>>>(h_b, rtab1, edges, offs, inv, updb);
  gemm_h_k<<<(B_ * MC / BM) * (E_ / BN), 256, 0, stream>>>(h_b, Wsb + (size_t)E_ * E_, updb,
                                                           Wnb + (size_t)E_ * E_, h_a);

  out_k<<<(B_ * MT * 192 + 255) / 256, 256, 0, stream>>>(h_a, rtab2, relation_ids,
                                                         head_idx, tail_idx, d_out,
                                                         (const ushort*)concept_table);
}